// Round 1
// baseline (365.090 us; speedup 1.0000x reference)
//
#include <hip/hip_runtime.h>

// Causal attention fwd: B=2, S=2048, H=16, D=128, fp32 in/out, bf16 MFMA compute.
constexpr int Bc = 2, Sc = 2048, Hc = 16, Dc = 128;
constexpr int RS = Hc * Dc;                 // seq-row stride in elements (2048)
constexpr float SCALE = 0.08838834764831845f;  // 1/sqrt(128)

constexpr int QBLK = 64;    // q rows per block (16 per wave)
constexpr int KVBLK = 32;   // kv rows per iteration
constexpr int NW = 4;       // waves per block
constexpr int KPAD = Dc + 8;     // 136 bf16 -> 272B row stride (16B aligned, conflict-light)
constexpr int PPAD = KVBLK + 8;  // 40 bf16 -> 80B row stride

typedef __attribute__((ext_vector_type(8))) short bf16x8;
typedef __attribute__((ext_vector_type(4))) float f32x4;

__device__ __forceinline__ unsigned short f2b(float f) {
  unsigned int u = __builtin_bit_cast(unsigned int, f);
  u += 0x7fff + ((u >> 16) & 1);   // round-to-nearest-even
  return (unsigned short)(u >> 16);
}

__global__ __launch_bounds__(256)
void fa_fwd(const float* __restrict__ Q, const float* __restrict__ K,
            const float* __restrict__ V, float* __restrict__ O) {
  __shared__ unsigned short Klds[KVBLK][KPAD];
  __shared__ unsigned short Plds[NW][16][PPAD];

  const int tid = threadIdx.x;
  const int wid = tid >> 6;
  const int lane = tid & 63;
  const int lq = lane & 15;   // A-frag row / C col
  const int g = lane >> 4;    // 16-lane group

  const int qblk = blockIdx.x;
  const int b = blockIdx.y >> 4;
  const int h = blockIdx.y & 15;

  const int q0 = qblk * QBLK;
  const int qw = q0 + wid * 16;   // this wave's q-tile base row

  const size_t base = (size_t)b * Sc * RS + (size_t)h * Dc;
  const float* Qp = Q + base;
  const float* Kp = K + base;
  const float* Vp = V + base;
  float* Op = O + base;

  // ---- Q fragments (A layout): row = qw+lq, k = 32c + 8g + e ----
  bf16x8 qf[4];
  {
    const float* qrow = Qp + (size_t)(qw + lq) * RS + 8 * g;
    #pragma unroll
    for (int c = 0; c < 4; ++c) {
      float4 f0 = *(const float4*)(qrow + 32 * c);
      float4 f1 = *(const float4*)(qrow + 32 * c + 4);
      bf16x8 v;
      v[0] = (short)f2b(f0.x); v[1] = (short)f2b(f0.y);
      v[2] = (short)f2b(f0.z); v[3] = (short)f2b(f0.w);
      v[4] = (short)f2b(f1.x); v[5] = (short)f2b(f1.y);
      v[6] = (short)f2b(f1.z); v[7] = (short)f2b(f1.w);
      qf[c] = v;
    }
  }

  f32x4 acc[8];
  #pragma unroll
  for (int dc = 0; dc < 8; ++dc) acc[dc] = f32x4{0.f, 0.f, 0.f, 0.f};
  float m_r[4] = {-1e30f, -1e30f, -1e30f, -1e30f};
  float l_r[4] = {0.f, 0.f, 0.f, 0.f};

  const int nkv = (q0 + QBLK) / KVBLK;   // causal: kv in [0, q0+QBLK)

  const int srow = tid >> 3;   // staging: 32 rows x 8 segs
  const int sseg = tid & 7;

  for (int kb = 0; kb < nkv; ++kb) {
    const int kv0 = kb * KVBLK;

    // ---- stage K tile -> LDS bf16 (coalesced) ----
    {
      const float* src = Kp + (size_t)(kv0 + srow) * RS + sseg * 16;
      float4 a0 = ((const float4*)src)[0];
      float4 a1 = ((const float4*)src)[1];
      float4 a2 = ((const float4*)src)[2];
      float4 a3 = ((const float4*)src)[3];
      bf16x8 w0, w1;
      w0[0] = (short)f2b(a0.x); w0[1] = (short)f2b(a0.y);
      w0[2] = (short)f2b(a0.z); w0[3] = (short)f2b(a0.w);
      w0[4] = (short)f2b(a1.x); w0[5] = (short)f2b(a1.y);
      w0[6] = (short)f2b(a1.z); w0[7] = (short)f2b(a1.w);
      w1[0] = (short)f2b(a2.x); w1[1] = (short)f2b(a2.y);
      w1[2] = (short)f2b(a2.z); w1[3] = (short)f2b(a2.w);
      w1[4] = (short)f2b(a3.x); w1[5] = (short)f2b(a3.y);
      w1[6] = (short)f2b(a3.z); w1[7] = (short)f2b(a3.w);
      *(bf16x8*)&Klds[srow][sseg * 16] = w0;
      *(bf16x8*)&Klds[srow][sseg * 16 + 8] = w1;
    }
    __syncthreads();   // staging complete

    // ---- QK^T: two 16x16 score tiles (kv cols 0-15, 16-31) ----
    f32x4 s0 = {0.f, 0.f, 0.f, 0.f}, s1 = {0.f, 0.f, 0.f, 0.f};
    #pragma unroll
    for (int c = 0; c < 4; ++c) {
      bf16x8 k0 = *(const bf16x8*)&Klds[lq][32 * c + 8 * g];
      bf16x8 k1 = *(const bf16x8*)&Klds[16 + lq][32 * c + 8 * g];
      s0 = __builtin_amdgcn_mfma_f32_16x16x32_bf16(qf[c], k0, s0, 0, 0, 0);
      s1 = __builtin_amdgcn_mfma_f32_16x16x32_bf16(qf[c], k1, s1, 0, 0, 0);
    }

    // ---- online softmax (rows 4g+r, col lq) ----
    float fac[4];
    #pragma unroll
    for (int r = 0; r < 4; ++r) {
      const int qrow = qw + 4 * g + r;
      float a = (kv0 + lq > qrow) ? -1e30f : s0[r] * SCALE;
      float c2 = (kv0 + 16 + lq > qrow) ? -1e30f : s1[r] * SCALE;
      float mx = fmaxf(a, c2);
      #pragma unroll
      for (int o = 8; o >= 1; o >>= 1) mx = fmaxf(mx, __shfl_xor(mx, o));
      const float mnew = fmaxf(m_r[r], mx);
      fac[r] = __expf(m_r[r] - mnew);
      m_r[r] = mnew;
      const float p0 = __expf(a - mnew);
      const float p1 = __expf(c2 - mnew);
      Plds[wid][4 * g + r][lq] = f2b(p0);
      Plds[wid][4 * g + r][16 + lq] = f2b(p1);
      float rs = p0 + p1;
      #pragma unroll
      for (int o = 8; o >= 1; o >>= 1) rs += __shfl_xor(rs, o);
      l_r[r] = l_r[r] * fac[r] + rs;
    }
    #pragma unroll
    for (int dc = 0; dc < 8; ++dc) {
      #pragma unroll
      for (int r = 0; r < 4; ++r) acc[dc][r] *= fac[r];
    }
    __syncthreads();   // P visible; also fences Klds reads before next restage

    // ---- PV: A = P (from LDS), B = V (direct global, bf16-converted) ----
    const bf16x8 pa = *(const bf16x8*)&Plds[wid][lq][8 * g];
    const float* vb = Vp + (size_t)(kv0 + 8 * g) * RS + lq;
    #pragma unroll
    for (int dc = 0; dc < 8; ++dc) {
      bf16x8 vf;
      #pragma unroll
      for (int e = 0; e < 8; ++e) vf[e] = (short)f2b(vb[(size_t)e * RS + 16 * dc]);
      acc[dc] = __builtin_amdgcn_mfma_f32_16x16x32_bf16(pa, vf, acc[dc], 0, 0, 0);
    }
  }

  // ---- epilogue: normalize and store fp32 ----
  float inv[4];
  #pragma unroll
  for (int r = 0; r < 4; ++r) inv[r] = 1.0f / l_r[r];
  float* orow = Op + (size_t)(qw + 4 * g) * RS + lq;
  #pragma unroll
  for (int dc = 0; dc < 8; ++dc) {
    #pragma unroll
    for (int r = 0; r < 4; ++r)
      orow[(size_t)r * RS + 16 * dc] = acc[dc][r] * inv[r];
  }
}

extern "C" void kernel_launch(void* const* d_in, const int* in_sizes, int n_in,
                              void* d_out, int out_size, void* d_ws, size_t ws_size,
                              hipStream_t stream) {
  const float* Q = (const float*)d_in[0];
  const float* K = (const float*)d_in[1];
  const float* V = (const float*)d_in[2];
  float* O = (float*)d_out;
  dim3 grid(Sc / QBLK, Bc * Hc);
  fa_fwd<<<grid, dim3(256), 0, stream>>>(Q, K, V, O);
}